// Round 20
// baseline (153.500 us; speedup 1.0000x reference)
//
#include <hip/hip_runtime.h>
#include <hip/hip_fp16.h>
#include <math.h>

#define NEG_SLOPE 0.2f
#define BSH 8              // 256 nodes per bucket
#define CAPB 6144          // phase-B LDS capacity (entries); mean ~4352

__device__ __forceinline__ float lrelu(float x) { return x > 0.f ? x : NEG_SLOPE * x; }

using half4 = __attribute__((ext_vector_type(4))) _Float16;
using half8 = __attribute__((ext_vector_type(8))) _Float16;
using f32x4 = __attribute__((ext_vector_type(4))) float;

// ---- typed 4-elem load (returns fp32) ----
template <typename TIn>
__device__ __forceinline__ float4 ld4(const TIn* p);
template <>
__device__ __forceinline__ float4 ld4<float>(const float* p) { return *(const float4*)p; }
template <>
__device__ __forceinline__ float4 ld4<_Float16>(const _Float16* p) {
    half4 v = *(const half4*)p;
    return make_float4((float)v[0], (float)v[1], (float)v[2], (float)v[3]);
}

// ---------------- MFMA gemm: h = x @ W^T (fp16 in, fp32 acc, fp16 out) ---------
template <int K, typename TIn>
__device__ __forceinline__ void gemm_mfma_body(const TIn* __restrict__ x,
                                               const float* __restrict__ W,
                                               const float* __restrict__ a_src,
                                               const float* __restrict__ a_dst,
                                               unsigned short* __restrict__ h_f16,
                                               float* __restrict__ es,
                                               float* __restrict__ ed,
                                               int N, int bid, _Float16* sm) {
    constexpr int KP = K + 8;
    _Float16* xs = sm;
    _Float16* ws = sm + 64 * KP;
    const int tid = threadIdx.x;
    const int n0 = bid * 64;

    constexpr int KV = K / 4;
    for (int idx = tid; idx < 64 * KV; idx += 256) {
        int r = idx / KV, kq = idx - r * KV;
        int n = n0 + r;
        float4 v = (n < N) ? ld4<TIn>(x + (size_t)n * K + kq * 4)
                           : make_float4(0.f, 0.f, 0.f, 0.f);
        half4 hv = {(_Float16)v.x, (_Float16)v.y, (_Float16)v.z, (_Float16)v.w};
        *(half4*)&xs[r * KP + kq * 4] = hv;
        float4 wv = *(const float4*)(W + (size_t)r * K + kq * 4);
        half4 wh = {(_Float16)wv.x, (_Float16)wv.y, (_Float16)wv.z, (_Float16)wv.w};
        *(half4*)&ws[r * KP + kq * 4] = wh;
    }
    __syncthreads();

    const int wv_ = tid >> 6, lane = tid & 63;
    const int lrow = lane & 15, g = lane >> 4;
    f32x4 acc0 = {0.f, 0.f, 0.f, 0.f}, acc1 = acc0, acc2 = acc0, acc3 = acc0;
#pragma unroll
    for (int ks = 0; ks < K / 32; ++ks) {
        const int ko = ks * 32 + g * 8;
        half8 af = *(const half8*)&xs[(wv_ * 16 + lrow) * KP + ko];
        half8 b0 = *(const half8*)&ws[(lrow) * KP + ko];
        half8 b1 = *(const half8*)&ws[(16 + lrow) * KP + ko];
        half8 b2 = *(const half8*)&ws[(32 + lrow) * KP + ko];
        half8 b3 = *(const half8*)&ws[(48 + lrow) * KP + ko];
        acc0 = __builtin_amdgcn_mfma_f32_16x16x32_f16(af, b0, acc0, 0, 0, 0);
        acc1 = __builtin_amdgcn_mfma_f32_16x16x32_f16(af, b1, acc1, 0, 0, 0);
        acc2 = __builtin_amdgcn_mfma_f32_16x16x32_f16(af, b2, acc2, 0, 0, 0);
        acc3 = __builtin_amdgcn_mfma_f32_16x16x32_f16(af, b3, acc3, 0, 0, 0);
    }
    __syncthreads();

    _Float16* ht = sm;
#pragma unroll
    for (int reg = 0; reg < 4; ++reg) {
        int r = wv_ * 16 + g * 4 + reg;   // C/D layout: row=(lane>>4)*4+reg
        ht[r * 72 +      lrow] = (_Float16)acc0[reg];
        ht[r * 72 + 16 + lrow] = (_Float16)acc1[reg];
        ht[r * 72 + 32 + lrow] = (_Float16)acc2[reg];
        ht[r * 72 + 48 + lrow] = (_Float16)acc3[reg];
    }
    __syncthreads();

    // phase2a: es/ed — one thread per (node, head)
    {
        int nl = tid >> 2, hd = tid & 3;
        half8 hA = *(const half8*)&ht[nl * 72 + hd * 16];
        half8 hB = *(const half8*)&ht[nl * 72 + hd * 16 + 8];
        const float4 s0 = *(const float4*)(a_src + hd * 16);
        const float4 s1 = *(const float4*)(a_src + hd * 16 + 4);
        const float4 s2 = *(const float4*)(a_src + hd * 16 + 8);
        const float4 s3 = *(const float4*)(a_src + hd * 16 + 12);
        const float4 d0 = *(const float4*)(a_dst + hd * 16);
        const float4 d1 = *(const float4*)(a_dst + hd * 16 + 4);
        const float4 d2 = *(const float4*)(a_dst + hd * 16 + 8);
        const float4 d3 = *(const float4*)(a_dst + hd * 16 + 12);
        float e1 = (float)hA[0]*s0.x + (float)hA[1]*s0.y + (float)hA[2]*s0.z + (float)hA[3]*s0.w
                 + (float)hA[4]*s1.x + (float)hA[5]*s1.y + (float)hA[6]*s1.z + (float)hA[7]*s1.w
                 + (float)hB[0]*s2.x + (float)hB[1]*s2.y + (float)hB[2]*s2.z + (float)hB[3]*s2.w
                 + (float)hB[4]*s3.x + (float)hB[5]*s3.y + (float)hB[6]*s3.z + (float)hB[7]*s3.w;
        float e2 = (float)hA[0]*d0.x + (float)hA[1]*d0.y + (float)hA[2]*d0.z + (float)hA[3]*d0.w
                 + (float)hA[4]*d1.x + (float)hA[5]*d1.y + (float)hA[6]*d1.z + (float)hA[7]*d1.w
                 + (float)hB[0]*d2.x + (float)hB[1]*d2.y + (float)hB[2]*d2.z + (float)hB[3]*d2.w
                 + (float)hB[4]*d3.x + (float)hB[5]*d3.y + (float)hB[6]*d3.z + (float)hB[7]*d3.w;
        int n = n0 + nl;
        if (n < N) {
            es[(size_t)n * 4 + hd] = e1;
            ed[(size_t)n * 4 + hd] = e2;
        }
    }
    // phase2b: coalesced h_f16 write from LDS
    for (int idx = tid; idx < 512; idx += 256) {
        int r = idx >> 3, c8 = (idx & 7) << 3;
        if (n0 + r < N)
            *(uint4*)(h_f16 + (size_t)(n0 + r) * 64 + c8) = *(const uint4*)&ht[r * 72 + c8];
    }
}

// ---- fused: blocks [0,NH) do the dst histogram; blocks [NH,..) do gemm layer-1 ----
template <int K>
__global__ __launch_bounds__(256) void gemm1_hist(const float* __restrict__ x,
                                                  const float* __restrict__ W,
                                                  const float* __restrict__ a_src,
                                                  const float* __restrict__ a_dst,
                                                  unsigned short* __restrict__ h_f16,
                                                  float* __restrict__ es,
                                                  float* __restrict__ ed, int N,
                                                  const int* __restrict__ dst,
                                                  int* __restrict__ hist_g,
                                                  int E, int Etot, int NBUCK, int nIter,
                                                  int NH) {
    __shared__ _Float16 sm[2 * 64 * (K + 8)];
    if ((int)blockIdx.x < NH) {
        int* hist = (int*)sm;
        int blk = blockIdx.x, tid = threadIdx.x;
        for (int i = tid; i < NBUCK; i += 256) hist[i] = 0;
        __syncthreads();
        int base = blk * nIter * 256;
        for (int i = 0; i < nIter; ++i) {
            int e = base + i * 256 + tid;
            if (e < Etot) {
                int d = (e < E) ? dst[e] : e - E;
                atomicAdd(&hist[d >> BSH], 1);
            }
        }
        __syncthreads();
        for (int i = tid; i < NBUCK; i += 256) hist_g[(size_t)blk * NBUCK + i] = hist[i];
        return;
    }
    gemm_mfma_body<K, float>(x, W, a_src, a_dst, h_f16, es, ed, N, blockIdx.x - NH, sm);
}

// ---- standalone gemm (layer 2, fp16 input) ----
template <int K, typename TIn>
__global__ __launch_bounds__(256) void gemm_mfma(const TIn* __restrict__ x,
                                                 const float* __restrict__ W,
                                                 const float* __restrict__ a_src,
                                                 const float* __restrict__ a_dst,
                                                 unsigned short* __restrict__ h_f16,
                                                 float* __restrict__ es,
                                                 float* __restrict__ ed, int N) {
    __shared__ _Float16 sm[2 * 64 * (K + 8)];
    gemm_mfma_body<K, TIn>(x, W, a_src, a_dst, h_f16, es, ed, N, blockIdx.x, sm);
}

// ---------------- CSR build ----------------
// per-bucket exclusive scan over up to 1024 hist rows (4 rows per thread)
__global__ __launch_bounds__(256) void bucket_scan_blocks(int* __restrict__ hist_g,
                                                          int* __restrict__ tot,
                                                          int NBUCK, int NBLK) {
    __shared__ int s[256];
    int b = blockIdx.x, tid = threadIdx.x;
    int r0 = tid * 4;
    int v0 = (r0 + 0 < NBLK) ? hist_g[(size_t)(r0 + 0) * NBUCK + b] : 0;
    int v1 = (r0 + 1 < NBLK) ? hist_g[(size_t)(r0 + 1) * NBUCK + b] : 0;
    int v2 = (r0 + 2 < NBLK) ? hist_g[(size_t)(r0 + 2) * NBUCK + b] : 0;
    int v3 = (r0 + 3 < NBLK) ? hist_g[(size_t)(r0 + 3) * NBUCK + b] : 0;
    int tsum = v0 + v1 + v2 + v3;
    s[tid] = tsum; __syncthreads();
#pragma unroll
    for (int off = 1; off < 256; off <<= 1) {
        int t = (tid >= off) ? s[tid - off] : 0;
        __syncthreads();
        s[tid] += t;
        __syncthreads();
    }
    int ex = s[tid] - tsum;   // exclusive over preceding threads
    if (r0 + 0 < NBLK) hist_g[(size_t)(r0 + 0) * NBUCK + b] = ex;
    if (r0 + 1 < NBLK) hist_g[(size_t)(r0 + 1) * NBUCK + b] = ex + v0;
    if (r0 + 2 < NBLK) hist_g[(size_t)(r0 + 2) * NBUCK + b] = ex + v0 + v1;
    if (r0 + 3 < NBLK) hist_g[(size_t)(r0 + 3) * NBUCK + b] = ex + v0 + v1 + v2;
    if (tid == 255) tot[b] = s[255];
}

// in-block inclusive scan of tot[0..NBUCK) into sv[512]
__device__ __forceinline__ void local_tot_scan(const int* __restrict__ tot, int* sv, int NBUCK) {
    int tid = threadIdx.x;
    sv[tid]       = (tid < NBUCK)       ? tot[tid]       : 0;
    sv[tid + 256] = (tid + 256 < NBUCK) ? tot[tid + 256] : 0;
    __syncthreads();
#pragma unroll
    for (int off = 1; off < 512; off <<= 1) {
        int a1 = (tid >= off) ? sv[tid - off] : 0;
        int a2 = (tid + 256 >= off) ? sv[tid + 256 - off] : 0;
        __syncthreads();
        sv[tid] += a1; sv[tid + 256] += a2;
        __syncthreads();
    }
}

__global__ __launch_bounds__(256) void bucket_scatter(const int* __restrict__ src,
                                                      const int* __restrict__ dst,
                                                      const int* __restrict__ hist_g,
                                                      const int* __restrict__ tot,
                                                      unsigned int* __restrict__ bbuf,
                                                      int E, int Etot, int NBUCK, int nIter) {
    __shared__ int sv[512];
    __shared__ int lcur[512];
    int blk = blockIdx.x, tid = threadIdx.x;
    local_tot_scan(tot, sv, NBUCK);
    for (int i = tid; i < NBUCK; i += 256)
        lcur[i] = (sv[i] - tot[i]) + hist_g[(size_t)blk * NBUCK + i];
    __syncthreads();
    int base = blk * nIter * 256;
    for (int i = 0; i < nIter; ++i) {
        int e = base + i * 256 + tid;
        if (e >= Etot) continue;
        int s, d;
        if (e < E) { s = src[e]; d = dst[e]; } else { s = d = e - E; }
        int pos = atomicAdd(&lcur[d >> BSH], 1);
        bbuf[pos] = (unsigned)s | ((unsigned)(d & ((1 << BSH) - 1)) << 24);
    }
}

__global__ __launch_bounds__(256) void bucket_build(const unsigned int* __restrict__ bbuf,
                                                    const int* __restrict__ tot,
                                                    int* __restrict__ col,
                                                    int* __restrict__ offs,
                                                    int N, int NBUCK, int Etot) {
    __shared__ int sv[512];
    __shared__ int cnt[256], lcur[256], s[256];
    __shared__ int ordered[CAPB];
    int b = blockIdx.x, tid = threadIdx.x;
    local_tot_scan(tot, sv, NBUCK);
    const int t  = tot[b];
    const int bb = sv[b] - t;            // exclusive bucket base
    const int n0 = b << BSH;
    if (b == 0 && tid == 0) offs[N] = Etot;
    cnt[tid] = 0;
    __syncthreads();
    for (int i = tid; i < t; i += 256) {
        unsigned v = bbuf[bb + i];
        atomicAdd(&cnt[v >> 24], 1);
    }
    __syncthreads();
    int c = cnt[tid];
    s[tid] = c; __syncthreads();
#pragma unroll
    for (int off = 1; off < 256; off <<= 1) {
        int tt = (tid >= off) ? s[tid - off] : 0;
        __syncthreads();
        s[tid] += tt;
        __syncthreads();
    }
    int ex = s[tid] - c;
    lcur[tid] = ex;
    if (n0 + tid < N) offs[n0 + tid] = bb + ex;
    __syncthreads();
    if (t <= CAPB) {
        for (int i = tid; i < t; i += 256) {
            unsigned v = bbuf[bb + i];
            int pos = atomicAdd(&lcur[v >> 24], 1);
            ordered[pos] = (int)(v & 0xFFFFFFu);
        }
        __syncthreads();
        for (int i = tid; i < t; i += 256) col[bb + i] = ordered[i];
    } else {  // fallback (never expected for near-uniform dst)
        for (int i = tid; i < t; i += 256) {
            unsigned v = bbuf[bb + i];
            int pos = atomicAdd(&lcur[v >> 24], 1);
            col[bb + pos] = (int)(v & 0xFFFFFFu);
        }
    }
}

// ---- batched D-deep accumulate for 2-node waves (4 edges/node/unit) ----
template <int D>
__device__ __forceinline__ void batch2n(int myCol, int cm1, int cnt32, int half,
                                        int eslot, int co, int hd, float edv,
                                        const float* __restrict__ es,
                                        const unsigned short* __restrict__ h_f16,
                                        float* acc, float& l) {
    int   sidx[D];
    float ev[D];
    uint4 hv[D];
#pragma unroll
    for (int d = 0; d < D; ++d)
        sidx[d] = __shfl(myCol, (half << 5) + min(eslot + 4 * d, cm1), 64);
#pragma unroll
    for (int d = 0; d < D; ++d)
        ev[d] = es[(size_t)sidx[d] * 4 + hd];
#pragma unroll
    for (int d = 0; d < D; ++d)
        hv[d] = *(const uint4*)(h_f16 + (size_t)sidx[d] * 64 + co * 8);
    float p[D];
#pragma unroll
    for (int d = 0; d < D; ++d)
        p[d] = (eslot + 4 * d < cnt32) ? __expf(lrelu(ev[d] + edv)) : 0.f;
#pragma unroll
    for (int d = 0; d < D; ++d) {
        union { uint4 u; __half h[8]; } u;
        u.u = hv[d];
        acc[0] += p[d] * __half2float(u.h[0]); acc[1] += p[d] * __half2float(u.h[1]);
        acc[2] += p[d] * __half2float(u.h[2]); acc[3] += p[d] * __half2float(u.h[3]);
        acc[4] += p[d] * __half2float(u.h[4]); acc[5] += p[d] * __half2float(u.h[5]);
        acc[6] += p[d] * __half2float(u.h[6]); acc[7] += p[d] * __half2float(u.h[7]);
        l += p[d];
    }
}

// ---------------- fused gather: TWO nodes per wave ------------------------------
template <bool FINAL>
__global__ __launch_bounds__(256) void gat_gather2n(const int* __restrict__ offs,
                                                    const int* __restrict__ col,
                                                    const float* __restrict__ es,
                                                    const float* __restrict__ ed,
                                                    const unsigned short* __restrict__ h_f16,
                                                    const float* __restrict__ b,
                                                    const float* __restrict__ fcw,
                                                    const float* __restrict__ fcb,
                                                    float* __restrict__ xo,
                                                    unsigned short* __restrict__ xo_h,
                                                    int N) {
    const int pair = (blockIdx.x * 256 + threadIdx.x) >> 6;
    const int lane = threadIdx.x & 63;
    const int half = lane >> 5, ll = lane & 31;
    const int eslot = ll >> 3, co = ll & 7, hd = co >> 1;
    const int w = pair * 2 + half;
    const bool vnode = w < N;

    int beg = 0, cnt = 1;
    if (vnode) { beg = offs[w]; cnt = offs[w + 1] - beg; }
    const float edv = vnode ? ed[(size_t)w * 4 + hd] : 0.f;

    const int cnt32 = min(cnt, 32);
    const int cm1 = cnt32 - 1;               // cnt >= 1 always (self-loop)
    int myCol = col[beg + min(ll, cm1)];
    int mcnt = max(cnt, __shfl_xor(cnt, 32, 64));

    float acc[8] = {0.f, 0.f, 0.f, 0.f, 0.f, 0.f, 0.f, 0.f};
    float l = 0.f;

    const int mcnt32 = min(mcnt, 32);
    if (mcnt32 <= 8) {
        batch2n<2>(myCol, cm1, cnt32, half, eslot, co, hd, edv, es, h_f16, acc, l);
    } else if (mcnt32 <= 16) {
        batch2n<4>(myCol, cm1, cnt32, half, eslot, co, hd, edv, es, h_f16, acc, l);
    } else if (mcnt32 <= 24) {
        batch2n<6>(myCol, cm1, cnt32, half, eslot, co, hd, edv, es, h_f16, acc, l);
    } else {
        batch2n<8>(myCol, cm1, cnt32, half, eslot, co, hd, edv, es, h_f16, acc, l);
        // loop fallback for nodes with cnt > 32 (P ~ 3e-4)
        for (int j = 32; j < mcnt; j += 4) {
            int k = j + eslot;
            bool valid = k < cnt;
            int s = valid ? col[beg + k] : 0;
            float a = es[(size_t)s * 4 + hd] + edv;
            float p = valid ? __expf(lrelu(a)) : 0.f;
            union { uint4 u; __half h[8]; } hv;
            hv.u = *(const uint4*)(h_f16 + (size_t)s * 64 + co * 8);
            acc[0] += p * __half2float(hv.h[0]); acc[1] += p * __half2float(hv.h[1]);
            acc[2] += p * __half2float(hv.h[2]); acc[3] += p * __half2float(hv.h[3]);
            acc[4] += p * __half2float(hv.h[4]); acc[5] += p * __half2float(hv.h[5]);
            acc[6] += p * __half2float(hv.h[6]); acc[7] += p * __half2float(hv.h[7]);
            l += p;
        }
    }

    // reduce across the 4 eslots (within each 32-lane half): masks 8,16
#pragma unroll
    for (int m = 8; m <= 16; m <<= 1) {
#pragma unroll
        for (int q = 0; q < 8; ++q) acc[q] += __shfl_xor(acc[q], m, 64);
        l += __shfl_xor(l, m, 64);
    }
    const float inv = 1.f / (l + 1e-16f);
    const float4 bv0 = *(const float4*)(b + co * 8);
    const float4 bv1 = *(const float4*)(b + co * 8 + 4);
    float v0 = acc[0] * inv + bv0.x, v1 = acc[1] * inv + bv0.y;
    float v2 = acc[2] * inv + bv0.z, v3 = acc[3] * inv + bv0.w;
    float v4 = acc[4] * inv + bv1.x, v5 = acc[5] * inv + bv1.y;
    float v6 = acc[6] * inv + bv1.z, v7 = acc[7] * inv + bv1.w;
    v0 = v0 > 0.f ? v0 : __expf(v0) - 1.f;
    v1 = v1 > 0.f ? v1 : __expf(v1) - 1.f;
    v2 = v2 > 0.f ? v2 : __expf(v2) - 1.f;
    v3 = v3 > 0.f ? v3 : __expf(v3) - 1.f;
    v4 = v4 > 0.f ? v4 : __expf(v4) - 1.f;
    v5 = v5 > 0.f ? v5 : __expf(v5) - 1.f;
    v6 = v6 > 0.f ? v6 : __expf(v6) - 1.f;
    v7 = v7 > 0.f ? v7 : __expf(v7) - 1.f;
    if (FINAL) {
        const float4 fw0 = *(const float4*)(fcw + co * 8);
        const float4 fw1 = *(const float4*)(fcw + co * 8 + 4);
        float t = v0 * fw0.x + v1 * fw0.y + v2 * fw0.z + v3 * fw0.w +
                  v4 * fw1.x + v5 * fw1.y + v6 * fw1.z + v7 * fw1.w;
#pragma unroll
        for (int m = 1; m <= 4; m <<= 1) t += __shfl_xor(t, m, 64);
        if (ll == 0 && vnode) xo[w] = t + fcb[0];
    } else {
        if (ll < 8 && vnode) {
            unsigned p0u = (unsigned)__half_as_ushort(__float2half_rn(v0)) |
                           ((unsigned)__half_as_ushort(__float2half_rn(v1)) << 16);
            unsigned p1u = (unsigned)__half_as_ushort(__float2half_rn(v2)) |
                           ((unsigned)__half_as_ushort(__float2half_rn(v3)) << 16);
            unsigned p2u = (unsigned)__half_as_ushort(__float2half_rn(v4)) |
                           ((unsigned)__half_as_ushort(__float2half_rn(v5)) << 16);
            unsigned p3u = (unsigned)__half_as_ushort(__float2half_rn(v6)) |
                           ((unsigned)__half_as_ushort(__float2half_rn(v7)) << 16);
            *(uint4*)(xo_h + (size_t)w * 64 + co * 8) = make_uint4(p0u, p1u, p2u, p3u);
        }
    }
}

extern "C" void kernel_launch(void* const* d_in, const int* in_sizes, int n_in,
                              void* d_out, int out_size, void* d_ws, size_t ws_size,
                              hipStream_t stream) {
    const float* x   = (const float*)d_in[0];
    const int*   ei  = (const int*)d_in[1];
    const float* w1  = (const float*)d_in[2];
    const float* as1 = (const float*)d_in[3];
    const float* ad1 = (const float*)d_in[4];
    const float* b1  = (const float*)d_in[5];
    const float* w2  = (const float*)d_in[6];
    const float* as2 = (const float*)d_in[7];
    const float* ad2 = (const float*)d_in[8];
    const float* b2  = (const float*)d_in[9];
    const float* fcw = (const float*)d_in[10];
    const float* fcb = (const float*)d_in[11];
    float* out = (float*)d_out;

    const int N = in_sizes[0] / 128;  // 100000
    const int E = in_sizes[1] / 2;    // 1600000
    const int Etot = E + N;
    const int* src = ei;
    const int* dst = ei + E;

    const int NBUCK = (N + 255) >> BSH;          // 391 (<=512)
    int CHe = 2048;
    while ((Etot + CHe - 1) / CHe > 1024) CHe *= 2;
    const int NBLK = (Etot + CHe - 1) / CHe;     // 831 (<=1024)
    const int nIter = CHe / 256;

    char* p = (char*)d_ws;
    unsigned short* h_f16 = (unsigned short*)p;  p += (size_t)N * 64 * 2;
    unsigned short* x2    = (unsigned short*)p;  p += (size_t)N * 64 * 2;
    float* es    = (float*)p;  p += (size_t)N * 4 * 4;
    float* ed    = (float*)p;  p += (size_t)N * 4 * 4;
    int* offs    = (int*)p;    p += (size_t)(N + 1) * 4;
    int* tot     = (int*)p;    p += (size_t)NBUCK * 4;
    int* hist_g  = (int*)p;    p += (size_t)NBLK * NBUCK * 4;
    int* col     = (int*)p;    p += (size_t)Etot * 4;
    unsigned int* bbuf = (unsigned int*)p;  p += (size_t)Etot * 4;

    dim3 blk(256);
    const int gN64t = (N + 63) / 64;             // 1563 gemm tiles
    const int nPair = (N + 1) / 2;               // 2 nodes per wave
    const int gW2   = (nPair * 64 + 255) / 256;  // 2-node-wave gather grid

    // ---- fused: dst histogram (blocks 0..NBLK) + layer-1 mfma gemm (rest) ----
    gemm1_hist<128><<<NBLK + gN64t, blk, 0, stream>>>(x, w1, as1, ad1, h_f16, es, ed, N,
                                                      dst, hist_g, E, Etot, NBUCK, nIter, NBLK);
    // ---- CSR build (shared by both layers) ----
    bucket_scan_blocks<<<NBUCK, blk, 0, stream>>>(hist_g, tot, NBUCK, NBLK);
    bucket_scatter<<<NBLK, blk, 0, stream>>>(src, dst, hist_g, tot, bbuf, E, Etot, NBUCK, nIter);
    bucket_build<<<NBUCK, blk, 0, stream>>>(bbuf, tot, col, offs, N, NBUCK, Etot);

    // ---- layer 1 gather ----
    gat_gather2n<false><<<gW2, blk, 0, stream>>>(offs, col, es, ed, h_f16, b1,
                                                 nullptr, nullptr, nullptr, x2, N);
    // ---- layer 2 ----
    gemm_mfma<64, _Float16><<<gN64t, blk, 0, stream>>>((const _Float16*)x2, w2, as2, ad2,
                                                       h_f16, es, ed, N);
    gat_gather2n<true><<<gW2, blk, 0, stream>>>(offs, col, es, ed, h_f16, b2,
                                                fcw, fcb, out, nullptr, N);
}

// Round 21
// 150.316 us; speedup vs baseline: 1.0212x; 1.0212x over previous
//
#include <hip/hip_runtime.h>
#include <hip/hip_fp16.h>
#include <math.h>

#define NEG_SLOPE 0.2f
#define BSH 8              // 256 nodes per bucket
#define CAPB 6144          // phase-B LDS capacity (entries); mean ~4352

__device__ __forceinline__ float lrelu(float x) { return x > 0.f ? x : NEG_SLOPE * x; }

using half4 = __attribute__((ext_vector_type(4))) _Float16;
using half8 = __attribute__((ext_vector_type(8))) _Float16;
using f32x4 = __attribute__((ext_vector_type(4))) float;

// ---- typed 4-elem load (returns fp32) ----
template <typename TIn>
__device__ __forceinline__ float4 ld4(const TIn* p);
template <>
__device__ __forceinline__ float4 ld4<float>(const float* p) { return *(const float4*)p; }
template <>
__device__ __forceinline__ float4 ld4<_Float16>(const _Float16* p) {
    half4 v = *(const half4*)p;
    return make_float4((float)v[0], (float)v[1], (float)v[2], (float)v[3]);
}

// ---------------- MFMA gemm: h = x @ W^T (fp16 in, fp32 acc, fp16 out) ---------
// 64x64 tile/block, 4 waves; wave w computes nodes [w*16,w*16+16) x all 64 cols
// via 4x mfma_f32_16x16x32_f16 per K=32 step. LDS stride K+8 halves keeps
// ds_read_b128 16B-aligned with only 2-way bank aliasing. Epilogue stages the
// h tile in LDS: coalesced global h_f16 write + fused es/ed attn-coef dots.
template <int K, typename TIn>
__device__ __forceinline__ void gemm_mfma_body(const TIn* __restrict__ x,
                                               const float* __restrict__ W,
                                               const float* __restrict__ a_src,
                                               const float* __restrict__ a_dst,
                                               unsigned short* __restrict__ h_f16,
                                               float* __restrict__ es,
                                               float* __restrict__ ed,
                                               int N, int bid, _Float16* sm) {
    constexpr int KP = K + 8;
    _Float16* xs = sm;
    _Float16* ws = sm + 64 * KP;
    const int tid = threadIdx.x;
    const int n0 = bid * 64;

    constexpr int KV = K / 4;
    for (int idx = tid; idx < 64 * KV; idx += 256) {
        int r = idx / KV, kq = idx - r * KV;
        int n = n0 + r;
        float4 v = (n < N) ? ld4<TIn>(x + (size_t)n * K + kq * 4)
                           : make_float4(0.f, 0.f, 0.f, 0.f);
        half4 hv = {(_Float16)v.x, (_Float16)v.y, (_Float16)v.z, (_Float16)v.w};
        *(half4*)&xs[r * KP + kq * 4] = hv;
        float4 wv = *(const float4*)(W + (size_t)r * K + kq * 4);
        half4 wh = {(_Float16)wv.x, (_Float16)wv.y, (_Float16)wv.z, (_Float16)wv.w};
        *(half4*)&ws[r * KP + kq * 4] = wh;
    }
    __syncthreads();

    const int wv_ = tid >> 6, lane = tid & 63;
    const int lrow = lane & 15, g = lane >> 4;
    f32x4 acc0 = {0.f, 0.f, 0.f, 0.f}, acc1 = acc0, acc2 = acc0, acc3 = acc0;
#pragma unroll
    for (int ks = 0; ks < K / 32; ++ks) {
        const int ko = ks * 32 + g * 8;
        half8 af = *(const half8*)&xs[(wv_ * 16 + lrow) * KP + ko];
        half8 b0 = *(const half8*)&ws[(lrow) * KP + ko];
        half8 b1 = *(const half8*)&ws[(16 + lrow) * KP + ko];
        half8 b2 = *(const half8*)&ws[(32 + lrow) * KP + ko];
        half8 b3 = *(const half8*)&ws[(48 + lrow) * KP + ko];
        acc0 = __builtin_amdgcn_mfma_f32_16x16x32_f16(af, b0, acc0, 0, 0, 0);
        acc1 = __builtin_amdgcn_mfma_f32_16x16x32_f16(af, b1, acc1, 0, 0, 0);
        acc2 = __builtin_amdgcn_mfma_f32_16x16x32_f16(af, b2, acc2, 0, 0, 0);
        acc3 = __builtin_amdgcn_mfma_f32_16x16x32_f16(af, b3, acc3, 0, 0, 0);
    }
    __syncthreads();

    // stage h tile in LDS (aliases xs; 64x72 halves fits both K variants)
    _Float16* ht = sm;
#pragma unroll
    for (int reg = 0; reg < 4; ++reg) {
        int r = wv_ * 16 + g * 4 + reg;   // C/D layout: row=(lane>>4)*4+reg
        ht[r * 72 +      lrow] = (_Float16)acc0[reg];
        ht[r * 72 + 16 + lrow] = (_Float16)acc1[reg];
        ht[r * 72 + 32 + lrow] = (_Float16)acc2[reg];
        ht[r * 72 + 48 + lrow] = (_Float16)acc3[reg];
    }
    __syncthreads();

    // phase2a: es/ed — one thread per (node, head)
    {
        int nl = tid >> 2, hd = tid & 3;
        half8 hA = *(const half8*)&ht[nl * 72 + hd * 16];
        half8 hB = *(const half8*)&ht[nl * 72 + hd * 16 + 8];
        const float4 s0 = *(const float4*)(a_src + hd * 16);
        const float4 s1 = *(const float4*)(a_src + hd * 16 + 4);
        const float4 s2 = *(const float4*)(a_src + hd * 16 + 8);
        const float4 s3 = *(const float4*)(a_src + hd * 16 + 12);
        const float4 d0 = *(const float4*)(a_dst + hd * 16);
        const float4 d1 = *(const float4*)(a_dst + hd * 16 + 4);
        const float4 d2 = *(const float4*)(a_dst + hd * 16 + 8);
        const float4 d3 = *(const float4*)(a_dst + hd * 16 + 12);
        float e1 = (float)hA[0]*s0.x + (float)hA[1]*s0.y + (float)hA[2]*s0.z + (float)hA[3]*s0.w
                 + (float)hA[4]*s1.x + (float)hA[5]*s1.y + (float)hA[6]*s1.z + (float)hA[7]*s1.w
                 + (float)hB[0]*s2.x + (float)hB[1]*s2.y + (float)hB[2]*s2.z + (float)hB[3]*s2.w
                 + (float)hB[4]*s3.x + (float)hB[5]*s3.y + (float)hB[6]*s3.z + (float)hB[7]*s3.w;
        float e2 = (float)hA[0]*d0.x + (float)hA[1]*d0.y + (float)hA[2]*d0.z + (float)hA[3]*d0.w
                 + (float)hA[4]*d1.x + (float)hA[5]*d1.y + (float)hA[6]*d1.z + (float)hA[7]*d1.w
                 + (float)hB[0]*d2.x + (float)hB[1]*d2.y + (float)hB[2]*d2.z + (float)hB[3]*d2.w
                 + (float)hB[4]*d3.x + (float)hB[5]*d3.y + (float)hB[6]*d3.z + (float)hB[7]*d3.w;
        int n = n0 + nl;
        if (n < N) {
            es[(size_t)n * 4 + hd] = e1;
            ed[(size_t)n * 4 + hd] = e2;
        }
    }
    // phase2b: coalesced h_f16 write from LDS
    for (int idx = tid; idx < 512; idx += 256) {
        int r = idx >> 3, c8 = (idx & 7) << 3;
        if (n0 + r < N)
            *(uint4*)(h_f16 + (size_t)(n0 + r) * 64 + c8) = *(const uint4*)&ht[r * 72 + c8];
    }
}

// ---- fused: blocks [0,NH) do the dst histogram; blocks [NH,..) do gemm layer-1 ----
template <int K>
__global__ __launch_bounds__(256) void gemm1_hist(const float* __restrict__ x,
                                                  const float* __restrict__ W,
                                                  const float* __restrict__ a_src,
                                                  const float* __restrict__ a_dst,
                                                  unsigned short* __restrict__ h_f16,
                                                  float* __restrict__ es,
                                                  float* __restrict__ ed, int N,
                                                  const int* __restrict__ dst,
                                                  int* __restrict__ hist_g,
                                                  int E, int Etot, int NBUCK, int nIter,
                                                  int NH) {
    __shared__ _Float16 sm[2 * 64 * (K + 8)];
    if ((int)blockIdx.x < NH) {
        int* hist = (int*)sm;
        int blk = blockIdx.x, tid = threadIdx.x;
        for (int i = tid; i < NBUCK; i += 256) hist[i] = 0;
        __syncthreads();
        int base = blk * nIter * 256;
        for (int i = 0; i < nIter; ++i) {
            int e = base + i * 256 + tid;
            if (e < Etot) {
                int d = (e < E) ? dst[e] : e - E;
                atomicAdd(&hist[d >> BSH], 1);
            }
        }
        __syncthreads();
        for (int i = tid; i < NBUCK; i += 256) hist_g[(size_t)blk * NBUCK + i] = hist[i];
        return;
    }
    gemm_mfma_body<K, float>(x, W, a_src, a_dst, h_f16, es, ed, N, blockIdx.x - NH, sm);
}

// ---- standalone gemm (layer 2, fp16 input) ----
template <int K, typename TIn>
__global__ __launch_bounds__(256) void gemm_mfma(const TIn* __restrict__ x,
                                                 const float* __restrict__ W,
                                                 const float* __restrict__ a_src,
                                                 const float* __restrict__ a_dst,
                                                 unsigned short* __restrict__ h_f16,
                                                 float* __restrict__ es,
                                                 float* __restrict__ ed, int N) {
    __shared__ _Float16 sm[2 * 64 * (K + 8)];
    gemm_mfma_body<K, TIn>(x, W, a_src, a_dst, h_f16, es, ed, N, blockIdx.x, sm);
}

// ---------------- CSR build ----------------
__global__ __launch_bounds__(256) void bucket_scan_blocks(int* __restrict__ hist_g,
                                                          int* __restrict__ tot,
                                                          int NBUCK, int NBLK) {
    __shared__ int s[256];
    int b = blockIdx.x, tid = threadIdx.x;
    int v = (tid < NBLK) ? hist_g[(size_t)tid * NBUCK + b] : 0;
    s[tid] = v; __syncthreads();
#pragma unroll
    for (int off = 1; off < 256; off <<= 1) {
        int t = (tid >= off) ? s[tid - off] : 0;
        __syncthreads();
        s[tid] += t;
        __syncthreads();
    }
    if (tid < NBLK) hist_g[(size_t)tid * NBUCK + b] = s[tid] - v;  // exclusive
    if (tid == 255) tot[b] = s[255];
}

// in-block inclusive scan of tot[0..NBUCK) into sv[512]
__device__ __forceinline__ void local_tot_scan(const int* __restrict__ tot, int* sv, int NBUCK) {
    int tid = threadIdx.x;
    sv[tid]       = (tid < NBUCK)       ? tot[tid]       : 0;
    sv[tid + 256] = (tid + 256 < NBUCK) ? tot[tid + 256] : 0;
    __syncthreads();
#pragma unroll
    for (int off = 1; off < 512; off <<= 1) {
        int a1 = (tid >= off) ? sv[tid - off] : 0;
        int a2 = (tid + 256 >= off) ? sv[tid + 256 - off] : 0;
        __syncthreads();
        sv[tid] += a1; sv[tid + 256] += a2;
        __syncthreads();
    }
}

__global__ __launch_bounds__(256) void bucket_scatter(const int* __restrict__ src,
                                                      const int* __restrict__ dst,
                                                      const int* __restrict__ hist_g,
                                                      const int* __restrict__ tot,
                                                      unsigned int* __restrict__ bbuf,
                                                      int E, int Etot, int NBUCK, int nIter) {
    __shared__ int sv[512];
    __shared__ int lcur[512];
    int blk = blockIdx.x, tid = threadIdx.x;
    local_tot_scan(tot, sv, NBUCK);
    for (int i = tid; i < NBUCK; i += 256)
        lcur[i] = (sv[i] - tot[i]) + hist_g[(size_t)blk * NBUCK + i];
    __syncthreads();
    int base = blk * nIter * 256;
    for (int i = 0; i < nIter; ++i) {
        int e = base + i * 256 + tid;
        if (e >= Etot) continue;
        int s, d;
        if (e < E) { s = src[e]; d = dst[e]; } else { s = d = e - E; }
        int pos = atomicAdd(&lcur[d >> BSH], 1);
        bbuf[pos] = (unsigned)s | ((unsigned)(d & ((1 << BSH) - 1)) << 24);
    }
}

__global__ __launch_bounds__(256) void bucket_build(const unsigned int* __restrict__ bbuf,
                                                    const int* __restrict__ tot,
                                                    int* __restrict__ col,
                                                    int* __restrict__ offs,
                                                    int N, int NBUCK, int Etot) {
    __shared__ int sv[512];
    __shared__ int cnt[256], lcur[256], s[256];
    __shared__ int ordered[CAPB];
    int b = blockIdx.x, tid = threadIdx.x;
    local_tot_scan(tot, sv, NBUCK);
    const int t  = tot[b];
    const int bb = sv[b] - t;            // exclusive bucket base
    const int n0 = b << BSH;
    if (b == 0 && tid == 0) offs[N] = Etot;
    cnt[tid] = 0;
    __syncthreads();
    for (int i = tid; i < t; i += 256) {
        unsigned v = bbuf[bb + i];
        atomicAdd(&cnt[v >> 24], 1);
    }
    __syncthreads();
    int c = cnt[tid];
    s[tid] = c; __syncthreads();
#pragma unroll
    for (int off = 1; off < 256; off <<= 1) {
        int tt = (tid >= off) ? s[tid - off] : 0;
        __syncthreads();
        s[tid] += tt;
        __syncthreads();
    }
    int ex = s[tid] - c;
    lcur[tid] = ex;
    if (n0 + tid < N) offs[n0 + tid] = bb + ex;
    __syncthreads();
    if (t <= CAPB) {
        for (int i = tid; i < t; i += 256) {
            unsigned v = bbuf[bb + i];
            int pos = atomicAdd(&lcur[v >> 24], 1);
            ordered[pos] = (int)(v & 0xFFFFFFu);
        }
        __syncthreads();
        for (int i = tid; i < t; i += 256) col[bb + i] = ordered[i];
    } else {  // fallback (never expected for near-uniform dst)
        for (int i = tid; i < t; i += 256) {
            unsigned v = bbuf[bb + i];
            int pos = atomicAdd(&lcur[v >> 24], 1);
            col[bb + pos] = (int)(v & 0xFFFFFFu);
        }
    }
}

// ---- batched D-deep accumulate for 2-node waves (4 edges/node/unit) ----
template <int D>
__device__ __forceinline__ void batch2n(int myCol, int cm1, int cnt32, int half,
                                        int eslot, int co, int hd, float edv,
                                        const float* __restrict__ es,
                                        const unsigned short* __restrict__ h_f16,
                                        float* acc, float& l) {
    int   sidx[D];
    float ev[D];
    uint4 hv[D];
#pragma unroll
    for (int d = 0; d < D; ++d)
        sidx[d] = __shfl(myCol, (half << 5) + min(eslot + 4 * d, cm1), 64);
#pragma unroll
    for (int d = 0; d < D; ++d)
        ev[d] = es[(size_t)sidx[d] * 4 + hd];
#pragma unroll
    for (int d = 0; d < D; ++d)
        hv[d] = *(const uint4*)(h_f16 + (size_t)sidx[d] * 64 + co * 8);
    float p[D];
#pragma unroll
    for (int d = 0; d < D; ++d)
        p[d] = (eslot + 4 * d < cnt32) ? __expf(lrelu(ev[d] + edv)) : 0.f;
#pragma unroll
    for (int d = 0; d < D; ++d) {
        union { uint4 u; __half h[8]; } u;
        u.u = hv[d];
        acc[0] += p[d] * __half2float(u.h[0]); acc[1] += p[d] * __half2float(u.h[1]);
        acc[2] += p[d] * __half2float(u.h[2]); acc[3] += p[d] * __half2float(u.h[3]);
        acc[4] += p[d] * __half2float(u.h[4]); acc[5] += p[d] * __half2float(u.h[5]);
        acc[6] += p[d] * __half2float(u.h[6]); acc[7] += p[d] * __half2float(u.h[7]);
        l += p[d];
    }
}

// ---------------- fused gather: TWO nodes per wave ------------------------------
// half = lane>>5 selects the node; ll = lane&31; eslot = ll>>3 in [0,4) handles
// edge j+eslot; co = ll&7 covers channels [8co,8co+8); head = co>>1. Fixed
// per-node costs (prologue, reduce, epilogue) are shared by 2 nodes; edge-work
// efficiency unchanged. Depth dispatch on the wave-uniform pair-max; register
// edge list caps at 32 per node with a loop fallback. Softmax no-max form.
template <bool FINAL>
__global__ __launch_bounds__(256) void gat_gather2n(const int* __restrict__ offs,
                                                    const int* __restrict__ col,
                                                    const float* __restrict__ es,
                                                    const float* __restrict__ ed,
                                                    const unsigned short* __restrict__ h_f16,
                                                    const float* __restrict__ b,
                                                    const float* __restrict__ fcw,
                                                    const float* __restrict__ fcb,
                                                    float* __restrict__ xo,
                                                    unsigned short* __restrict__ xo_h,
                                                    int N) {
    const int pair = (blockIdx.x * 256 + threadIdx.x) >> 6;
    const int lane = threadIdx.x & 63;
    const int half = lane >> 5, ll = lane & 31;
    const int eslot = ll >> 3, co = ll & 7, hd = co >> 1;
    const int w = pair * 2 + half;
    const bool vnode = w < N;

    int beg = 0, cnt = 1;
    if (vnode) { beg = offs[w]; cnt = offs[w + 1] - beg; }
    const float edv = vnode ? ed[(size_t)w * 4 + hd] : 0.f;

    const int cnt32 = min(cnt, 32);
    const int cm1 = cnt32 - 1;               // cnt >= 1 always (self-loop)
    int myCol = col[beg + min(ll, cm1)];
    int mcnt = max(cnt, __shfl_xor(cnt, 32, 64));

    float acc[8] = {0.f, 0.f, 0.f, 0.f, 0.f, 0.f, 0.f, 0.f};
    float l = 0.f;

    const int mcnt32 = min(mcnt, 32);
    if (mcnt32 <= 8) {
        batch2n<2>(myCol, cm1, cnt32, half, eslot, co, hd, edv, es, h_f16, acc, l);
    } else if (mcnt32 <= 16) {
        batch2n<4>(myCol, cm1, cnt32, half, eslot, co, hd, edv, es, h_f16, acc, l);
    } else if (mcnt32 <= 24) {
        batch2n<6>(myCol, cm1, cnt32, half, eslot, co, hd, edv, es, h_f16, acc, l);
    } else {
        batch2n<8>(myCol, cm1, cnt32, half, eslot, co, hd, edv, es, h_f16, acc, l);
        // loop fallback for nodes with cnt > 32 (P ~ 3e-4)
        for (int j = 32; j < mcnt; j += 4) {
            int k = j + eslot;
            bool valid = k < cnt;
            int s = valid ? col[beg + k] : 0;
            float a = es[(size_t)s * 4 + hd] + edv;
            float p = valid ? __expf(lrelu(a)) : 0.f;
            union { uint4 u; __half h[8]; } hv;
            hv.u = *(const uint4*)(h_f16 + (size_t)s * 64 + co * 8);
            acc[0] += p * __half2float(hv.h[0]); acc[1] += p * __half2float(hv.h[1]);
            acc[2] += p * __half2float(hv.h[2]); acc[3] += p * __half2float(hv.h[3]);
            acc[4] += p * __half2float(hv.h[4]); acc[5] += p * __half2float(hv.h[5]);
            acc[6] += p * __half2float(hv.h[6]); acc[7] += p * __half2float(hv.h[7]);
            l += p;
        }
    }

    // reduce across the 4 eslots (within each 32-lane half): masks 8,16
#pragma unroll
    for (int m = 8; m <= 16; m <<= 1) {
#pragma unroll
        for (int q = 0; q < 8; ++q) acc[q] += __shfl_xor(acc[q], m, 64);
        l += __shfl_xor(l, m, 64);
    }
    const float inv = 1.f / (l + 1e-16f);
    const float4 bv0 = *(const float4*)(b + co * 8);
    const float4 bv1 = *(const float4*)(b + co * 8 + 4);
    float v0 = acc[0] * inv + bv0.x, v1 = acc[1] * inv + bv0.y;
    float v2 = acc[2] * inv + bv0.z, v3 = acc[3] * inv + bv0.w;
    float v4 = acc[4] * inv + bv1.x, v5 = acc[5] * inv + bv1.y;
    float v6 = acc[6] * inv + bv1.z, v7 = acc[7] * inv + bv1.w;
    v0 = v0 > 0.f ? v0 : __expf(v0) - 1.f;
    v1 = v1 > 0.f ? v1 : __expf(v1) - 1.f;
    v2 = v2 > 0.f ? v2 : __expf(v2) - 1.f;
    v3 = v3 > 0.f ? v3 : __expf(v3) - 1.f;
    v4 = v4 > 0.f ? v4 : __expf(v4) - 1.f;
    v5 = v5 > 0.f ? v5 : __expf(v5) - 1.f;
    v6 = v6 > 0.f ? v6 : __expf(v6) - 1.f;
    v7 = v7 > 0.f ? v7 : __expf(v7) - 1.f;
    if (FINAL) {
        const float4 fw0 = *(const float4*)(fcw + co * 8);
        const float4 fw1 = *(const float4*)(fcw + co * 8 + 4);
        float t = v0 * fw0.x + v1 * fw0.y + v2 * fw0.z + v3 * fw0.w +
                  v4 * fw1.x + v5 * fw1.y + v6 * fw1.z + v7 * fw1.w;
#pragma unroll
        for (int m = 1; m <= 4; m <<= 1) t += __shfl_xor(t, m, 64);
        if (ll == 0 && vnode) xo[w] = t + fcb[0];
    } else {
        if (ll < 8 && vnode) {
            unsigned p0u = (unsigned)__half_as_ushort(__float2half_rn(v0)) |
                           ((unsigned)__half_as_ushort(__float2half_rn(v1)) << 16);
            unsigned p1u = (unsigned)__half_as_ushort(__float2half_rn(v2)) |
                           ((unsigned)__half_as_ushort(__float2half_rn(v3)) << 16);
            unsigned p2u = (unsigned)__half_as_ushort(__float2half_rn(v4)) |
                           ((unsigned)__half_as_ushort(__float2half_rn(v5)) << 16);
            unsigned p3u = (unsigned)__half_as_ushort(__float2half_rn(v6)) |
                           ((unsigned)__half_as_ushort(__float2half_rn(v7)) << 16);
            *(uint4*)(xo_h + (size_t)w * 64 + co * 8) = make_uint4(p0u, p1u, p2u, p3u);
        }
    }
}

extern "C" void kernel_launch(void* const* d_in, const int* in_sizes, int n_in,
                              void* d_out, int out_size, void* d_ws, size_t ws_size,
                              hipStream_t stream) {
    const float* x   = (const float*)d_in[0];
    const int*   ei  = (const int*)d_in[1];
    const float* w1  = (const float*)d_in[2];
    const float* as1 = (const float*)d_in[3];
    const float* ad1 = (const float*)d_in[4];
    const float* b1  = (const float*)d_in[5];
    const float* w2  = (const float*)d_in[6];
    const float* as2 = (const float*)d_in[7];
    const float* ad2 = (const float*)d_in[8];
    const float* b2  = (const float*)d_in[9];
    const float* fcw = (const float*)d_in[10];
    const float* fcb = (const float*)d_in[11];
    float* out = (float*)d_out;

    const int N = in_sizes[0] / 128;  // 100000
    const int E = in_sizes[1] / 2;    // 1600000
    const int Etot = E + N;
    const int* src = ei;
    const int* dst = ei + E;

    const int NBUCK = (N + 255) >> BSH;          // 391 (<=512)
    int CHe = 8192;
    while ((Etot + CHe - 1) / CHe > 256) CHe *= 2;
    const int NBLK = (Etot + CHe - 1) / CHe;     // 208 (<=256)
    const int nIter = CHe / 256;

    char* p = (char*)d_ws;
    unsigned short* h_f16 = (unsigned short*)p;  p += (size_t)N * 64 * 2;
    unsigned short* x2    = (unsigned short*)p;  p += (size_t)N * 64 * 2;
    float* es    = (float*)p;  p += (size_t)N * 4 * 4;
    float* ed    = (float*)p;  p += (size_t)N * 4 * 4;
    int* offs    = (int*)p;    p += (size_t)(N + 1) * 4;
    int* tot     = (int*)p;    p += (size_t)NBUCK * 4;
    int* hist_g  = (int*)p;    p += (size_t)NBLK * NBUCK * 4;
    int* col     = (int*)p;    p += (size_t)Etot * 4;
    unsigned int* bbuf = (unsigned int*)p;  p += (size_t)Etot * 4;

    dim3 blk(256);
    const int gN64t = (N + 63) / 64;             // 1563 gemm tiles
    const int nPair = (N + 1) / 2;               // 2 nodes per wave
    const int gW2   = (nPair * 64 + 255) / 256;  // 2-node-wave gather grid

    // ---- fused: dst histogram (blocks 0..NBLK) + layer-1 mfma gemm (rest) ----
    gemm1_hist<128><<<NBLK + gN64t, blk, 0, stream>>>(x, w1, as1, ad1, h_f16, es, ed, N,
                                                      dst, hist_g, E, Etot, NBUCK, nIter, NBLK);
    // ---- CSR build (shared by both layers) ----
    bucket_scan_blocks<<<NBUCK, blk, 0, stream>>>(hist_g, tot, NBUCK, NBLK);
    bucket_scatter<<<NBLK, blk, 0, stream>>>(src, dst, hist_g, tot, bbuf, E, Etot, NBUCK, nIter);
    bucket_build<<<NBUCK, blk, 0, stream>>>(bbuf, tot, col, offs, N, NBUCK, Etot);

    // ---- layer 1 gather ----
    gat_gather2n<false><<<gW2, blk, 0, stream>>>(offs, col, es, ed, h_f16, b1,
                                                 nullptr, nullptr, nullptr, x2, N);
    // ---- layer 2 ----
    gemm_mfma<64, _Float16><<<gN64t, blk, 0, stream>>>((const _Float16*)x2, w2, as2, ad2,
                                                       h_f16, es, ed, N);
    gat_gather2n<true><<<gW2, blk, 0, stream>>>(offs, col, es, ed, h_f16, b2,
                                                fcw, fcb, out, nullptr, N);
}